// Round 3
// baseline (4182.120 us; speedup 1.0000x reference)
//
#include <hip/hip_runtime.h>

#define B_ 128
#define D_ 512
#define T_ 33
#define L_ 32
#define V_ 10000
#define NWG 128

typedef short short8 __attribute__((ext_vector_type(8)));
typedef float f32x4 __attribute__((ext_vector_type(4)));

__device__ __forceinline__ short f2bf_rne(float f) {
    unsigned u = __builtin_bit_cast(unsigned, f);
    unsigned r = (u + 0x7FFFu + ((u >> 16) & 1u)) >> 16;
    return (short)r;
}
// truncation split: v ~= hi + lo with ~17 mantissa bits total
__device__ __forceinline__ void split2(float v, short& hi, short& lo) {
    unsigned u = __builtin_bit_cast(unsigned, v);
    hi = (short)(u >> 16);
    float hif = __builtin_bit_cast(float, u & 0xFFFF0000u);
    lo = (short)(__builtin_bit_cast(unsigned, v - hif) >> 16);
}
__device__ __forceinline__ float sigm(float x) {
    return 1.0f / (1.0f + __expf(-x));
}

// LLC-coherent (L1+L2 bypass) accesses: system-scope relaxed atomics lower to
// global_load/store_dword with sc0+sc1 — no cache-maintenance walks, fully
// coherent across XCDs. Compiler schedules/pipelines them like normal loads.
__device__ __forceinline__ unsigned llc_ldu(const void* p) {
    return __hip_atomic_load((const unsigned*)p, __ATOMIC_RELAXED,
                             __HIP_MEMORY_SCOPE_SYSTEM);
}
__device__ __forceinline__ float llc_ldf(const void* p) {
    return __builtin_bit_cast(float, llc_ldu(p));
}
__device__ __forceinline__ void llc_stu(void* p, unsigned v) {
    __hip_atomic_store((unsigned*)p, v, __ATOMIC_RELAXED,
                       __HIP_MEMORY_SCOPE_SYSTEM);
}

// ---------------------------------------------------------------------------
// prep: split X (features|emb) into hi/lo bf16, fc_W -> bf16 (RNE), zero sync
// ---------------------------------------------------------------------------
__global__ void prep_kernel(const float* __restrict__ features,
                            const int* __restrict__ caption,
                            const float* __restrict__ embW,
                            const float* __restrict__ fcW,
                            short* __restrict__ Xhi,
                            short* __restrict__ Xlo,
                            short* __restrict__ fcWb,
                            int* __restrict__ syncv) {
    const long NX = (long)T_ * B_ * D_;          // 2,162,688
    const long NW = (long)V_ * D_;               // 5,120,000
    const long total = NX + NW;
    long gid = (long)blockIdx.x * blockDim.x + threadIdx.x;
    if (gid == 0) { syncv[0] = 0; syncv[1] = 0; }
    for (long idx = gid; idx < total; idx += (long)gridDim.x * blockDim.x) {
        if (idx < NX) {
            int t = (int)(idx / (B_ * D_));
            int r = (int)(idx % (B_ * D_));
            int b = r >> 9;
            int d = r & 511;
            float v;
            if (t == 0) v = features[r];
            else        v = embW[(long)caption[b * L_ + (t - 1)] * D_ + d];
            short hi, lo;
            split2(v, hi, lo);
            Xhi[idx] = hi;
            Xlo[idx] = lo;
        } else {
            long j = idx - NX;
            fcWb[j] = f2bf_rne(fcW[j]);
        }
    }
}

// ---------------------------------------------------------------------------
// Persistent LSTM, split-bf16 MFMA (hi/lo x3 products => ~fp32 precision).
// 128 WGs; WG w owns d-cols [4w, 4w+4) across all 4 gates, both layers.
// LN of the h-carry folded into layer-0 W_hh (gamma pre-scaled, beta->bias).
//
// Coherence design (round 3): ZERO cache-maintenance ops in the main loop.
//   - all cross-WG data (H0 packed hi|lo uints, H1f fp32) is accessed ONLY
//     via sc0+sc1 (LLC-coherent) loads/stores -> no stale L1/L2 copies can
//     exist, so no acquire-inv / release-wbl2 walks are needed at all.
//   - barrier = single monotonic counter: arrive = relaxed fetch_add after
//     __syncthreads (vmcnt0 drains the LLC stores), wait = relaxed poll.
//   - x-half MFMAs (X-only dependency) issued between arrive and wait to
//     hide barrier propagation latency.
// ---------------------------------------------------------------------------
__global__ __launch_bounds__(256)
void lstm_persist(const short* __restrict__ Xhi, const short* __restrict__ Xlo,
                  const float* __restrict__ Wih, const float* __restrict__ Whh,
                  const float* __restrict__ bih, const float* __restrict__ bhh,
                  const float* __restrict__ lng, const float* __restrict__ lnb,
                  unsigned* __restrict__ H0p, float* __restrict__ H1f,
                  short* __restrict__ Hnb, int* __restrict__ syncv) {
    __shared__ __align__(16) short Wh[2][16][1032];   // 66 KB (hi)
    __shared__ __align__(16) short Wo[2][16][1032];   // 66 KB (lo)
    __shared__ float gbuf[128][17];
    __shared__ float carr[128][4];
    __shared__ float rs_s[128], murs_s[128];
    __shared__ float gam_s[512], bet_s[512];
    __shared__ float bias_s[2][16];
    __shared__ float bconst_s[16];

    const int tid  = threadIdx.x;
    const int w    = blockIdx.x;
    const int d0   = w * 4;
    const int wave = tid >> 6;
    const int lane = tid & 63;
    const int wm   = wave * 32;
    const int n    = lane & 15;
    const int kq   = (lane >> 4) * 8;

    // ---------------- preload ----------------
    for (int idx = tid; idx < 512; idx += 256) {
        gam_s[idx] = lng[idx];
        bet_s[idx] = lnb[idx];
    }
    if (tid < 32) {
        int l = tid >> 4, nn = tid & 15;
        int row = (nn >> 2) * 512 + d0 + (nn & 3);
        bias_s[l][nn] = bih[l * 2048 + row] + bhh[l * 2048 + row];
    }
    for (int idx = tid; idx < 2 * 16 * 1024; idx += 256) {
        int l = idx >> 14;
        int nn = (idx >> 10) & 15;
        int k = idx & 1023;
        int row = (nn >> 2) * 512 + d0 + (nn & 3);
        float v = (k < 512) ? Wih[((long)(l * 2048 + row)) * 512 + k]
                            : Whh[((long)(l * 2048 + row)) * 512 + (k - 512)];
        if (l == 0 && k >= 512) v *= lng[k - 512];   // fold gamma into Whh0
        short hi, lo;
        split2(v, hi, lo);
        Wh[l][nn][k] = hi;
        Wo[l][nn][k] = lo;
    }
    // bconst[c] = sum_k beta[k] * Whh0[row(c)][k]  (unfolded weights)
    {
        const int c = tid >> 4, kc = tid & 15;
        const int row = (c >> 2) * 512 + d0 + (c & 3);
        float s = 0.f;
        for (int k = kc * 32; k < kc * 32 + 32; ++k)
            s += lnb[k] * Whh[(long)row * 512 + k];
        gbuf[c][kc] = s;
    }
    for (int idx = tid; idx < 512; idx += 256) carr[idx >> 2][idx & 3] = 0.f;
    __syncthreads();
    if (tid < 16) {
        float s2 = 0.f;
        for (int i = 0; i < 16; ++i) s2 += gbuf[tid][i];
        bconst_s[tid] = s2;
    }
    __syncthreads();

    int* cnt = syncv;
    int nb = 0;   // barriers arrived at (local, lockstep across all threads)

    // arrive: __syncthreads drains every wave's LLC stores (vmcnt0 before
    // s_barrier), then one relaxed system-scope fetch_add. No fences.
    auto arrive = [&]() {
        __syncthreads();
        if (tid == 0)
            __hip_atomic_fetch_add(cnt, 1, __ATOMIC_RELAXED,
                                   __HIP_MEMORY_SCOPE_SYSTEM);
        ++nb;
    };
    // wait: relaxed system-scope polls of the monotonic counter. No fences —
    // all shared data lives at the LLC (sc0+sc1 on every access).
    auto wait_bar = [&]() {
        if (tid == 0) {
            const int tgt = nb * NWG;
            while (__hip_atomic_load(cnt, __ATOMIC_RELAXED,
                                     __HIP_MEMORY_SCOPE_SYSTEM) < tgt)
                __builtin_amdgcn_s_sleep(1);
        }
        __syncthreads();
    };

    // LN row stats of H1f, 2 threads per row.
    auto ln_stats = [&]() {
        const int row = tid & 127, half = tid >> 7;
        const unsigned* hp = (const unsigned*)&H1f[row * 512 + half * 256];
        float s = 0.f, s2 = 0.f;
        #pragma unroll 16
        for (int i = 0; i < 256; ++i) {
            float v = __builtin_bit_cast(float, llc_ldu(&hp[i]));
            s  += v;
            s2 += v * v;
        }
        gbuf[row][half * 2]     = s;
        gbuf[row][half * 2 + 1] = s2;
        __syncthreads();
        if (tid < 128) {
            const float ss  = gbuf[tid][0] + gbuf[tid][2];
            const float ss2 = gbuf[tid][1] + gbuf[tid][3];
            const float mu  = ss * (1.0f / 512.0f);
            const float var = ss2 * (1.0f / 512.0f) - mu * mu;
            const float rs  = rsqrtf(var + 1e-5f);
            rs_s[tid]   = rs;
            murs_s[tid] = mu * rs;
        }
        __syncthreads();
    };

    const int rA0 = (wm + n) * 512;
    const int rA1 = (wm + 16 + n) * 512;
    const int rq  = (lane >> 4) * 4;

    for (int t = 0; t < T_; ++t) {
        const short* xh = Xhi + (long)t * B_ * D_;
        const short* xl = Xlo + (long)t * B_ * D_;

        // ================= phase 0 (layer 0) =================
        {
            f32x4 acc0 = {0.f, 0.f, 0.f, 0.f};
            f32x4 acc1 = {0.f, 0.f, 0.f, 0.f};
            // x-half: depends only on X — runs while the H1 barrier propagates
            #pragma unroll 4
            for (int kc = 0; kc < 16; ++kc) {
                const int kg = kc * 32 + kq;
                short8 bh = *(const short8*)&Wh[0][n][kg];
                short8 bl = *(const short8*)&Wo[0][n][kg];
                short8 ah0 = *(const short8*)&xh[rA0 + kg];
                short8 al0 = *(const short8*)&xl[rA0 + kg];
                short8 ah1 = *(const short8*)&xh[rA1 + kg];
                short8 al1 = *(const short8*)&xl[rA1 + kg];
                acc0 = __builtin_amdgcn_mfma_f32_16x16x32_bf16(ah0, bh, acc0, 0, 0, 0);
                acc0 = __builtin_amdgcn_mfma_f32_16x16x32_bf16(ah0, bl, acc0, 0, 0, 0);
                acc0 = __builtin_amdgcn_mfma_f32_16x16x32_bf16(al0, bh, acc0, 0, 0, 0);
                acc1 = __builtin_amdgcn_mfma_f32_16x16x32_bf16(ah1, bh, acc1, 0, 0, 0);
                acc1 = __builtin_amdgcn_mfma_f32_16x16x32_bf16(ah1, bl, acc1, 0, 0, 0);
                acc1 = __builtin_amdgcn_mfma_f32_16x16x32_bf16(al1, bh, acc1, 0, 0, 0);
            }
            if (t > 0) {
                wait_bar();          // H1f(t-1) now at the LLC
                ln_stats();          // rs_s/murs_s of h1(t-1)
                // h-half: H1 fp32 via LLC loads, LN applied inline
                const float r0 = rs_s[wm + n],      m0 = murs_s[wm + n];
                const float r1 = rs_s[wm + 16 + n], m1 = murs_s[wm + 16 + n];
                #pragma unroll 2
                for (int kc = 0; kc < 16; ++kc) {
                    const int kh = kc * 32 + kq;
                    short8 bh = *(const short8*)&Wh[0][n][512 + kh];
                    short8 bl = *(const short8*)&Wo[0][n][512 + kh];
                    float va[8], vb[8];
                    #pragma unroll
                    for (int j = 0; j < 8; ++j) {
                        va[j] = llc_ldf(&H1f[rA0 + kh + j]);
                        vb[j] = llc_ldf(&H1f[rA1 + kh + j]);
                    }
                    short8 ah0, al0, ah1, al1;
                    #pragma unroll
                    for (int j = 0; j < 8; ++j) {
                        float f0 = fmaf(va[j], r0, -m0);
                        float f1 = fmaf(vb[j], r1, -m1);
                        short h_, l_;
                        split2(f0, h_, l_); ah0[j] = h_; al0[j] = l_;
                        split2(f1, h_, l_); ah1[j] = h_; al1[j] = l_;
                    }
                    acc0 = __builtin_amdgcn_mfma_f32_16x16x32_bf16(ah0, bh, acc0, 0, 0, 0);
                    acc0 = __builtin_amdgcn_mfma_f32_16x16x32_bf16(ah0, bl, acc0, 0, 0, 0);
                    acc0 = __builtin_amdgcn_mfma_f32_16x16x32_bf16(al0, bh, acc0, 0, 0, 0);
                    acc1 = __builtin_amdgcn_mfma_f32_16x16x32_bf16(ah1, bh, acc1, 0, 0, 0);
                    acc1 = __builtin_amdgcn_mfma_f32_16x16x32_bf16(ah1, bl, acc1, 0, 0, 0);
                    acc1 = __builtin_amdgcn_mfma_f32_16x16x32_bf16(al1, bh, acc1, 0, 0, 0);
                }
                // materialize LN'd bf16 rows of h1(t-1) for the FC GEMM
                // (safe: H1f rewritten only after ALL WGs pass barrier 2t+1,
                //  which we arrive at below, after these reads)
                if (w < 32 && t >= 2) {
                    const int rb = w * 4;
                    for (int idx = tid; idx < 2048; idx += 256) {
                        const int m = rb + (idx >> 9), k = idx & 511;
                        const float v = llc_ldf(&H1f[m * 512 + k]);
                        const float o = fmaf(fmaf(v, rs_s[m], -murs_s[m]), gam_s[k], bet_s[k]);
                        Hnb[(((long)(t - 2)) * B_ + m) * D_ + k] = f2bf_rne(o);
                    }
                }
            }
            const float bs = bias_s[0][n] + (t > 0 ? bconst_s[n] : 0.f);
            #pragma unroll
            for (int r = 0; r < 4; ++r) {
                gbuf[wm + rq + r][n]      = acc0[r] + bs;
                gbuf[wm + 16 + rq + r][n] = acc1[r] + bs;
            }
            __syncthreads();
            #pragma unroll
            for (int it = tid; it < 512; it += 256) {
                const int m = it >> 2, d = it & 3;
                const float gi = gbuf[m][d],     gf = gbuf[m][4 + d];
                const float gg = gbuf[m][8 + d], go = gbuf[m][12 + d];
                const float cn = sigm(gf) * carr[m][d] + sigm(gi) * tanhf(gg);
                carr[m][d] = cn;
                const float hv = sigm(go) * tanhf(cn);
                short hi_, lo_;
                split2(hv, hi_, lo_);
                const unsigned pk = (unsigned)(unsigned short)hi_
                                  | ((unsigned)(unsigned short)lo_ << 16);
                llc_stu(&H0p[m * 512 + d0 + d], pk);
            }
            arrive();   // barrier 2t+1: publish H0(t)
        }

        // ================= phase 1 (layer 1) =================
        {
            f32x4 acc0 = {0.f, 0.f, 0.f, 0.f};
            f32x4 acc1 = {0.f, 0.f, 0.f, 0.f};
            // x-half first: hides the H0 barrier propagation
            #pragma unroll 4
            for (int kc = 0; kc < 16; ++kc) {
                const int kg = kc * 32 + kq;
                short8 bh = *(const short8*)&Wh[1][n][kg];
                short8 bl = *(const short8*)&Wo[1][n][kg];
                short8 ah0 = *(const short8*)&xh[rA0 + kg];
                short8 al0 = *(const short8*)&xl[rA0 + kg];
                short8 ah1 = *(const short8*)&xh[rA1 + kg];
                short8 al1 = *(const short8*)&xl[rA1 + kg];
                acc0 = __builtin_amdgcn_mfma_f32_16x16x32_bf16(ah0, bh, acc0, 0, 0, 0);
                acc0 = __builtin_amdgcn_mfma_f32_16x16x32_bf16(ah0, bl, acc0, 0, 0, 0);
                acc0 = __builtin_amdgcn_mfma_f32_16x16x32_bf16(al0, bh, acc0, 0, 0, 0);
                acc1 = __builtin_amdgcn_mfma_f32_16x16x32_bf16(ah1, bh, acc1, 0, 0, 0);
                acc1 = __builtin_amdgcn_mfma_f32_16x16x32_bf16(ah1, bl, acc1, 0, 0, 0);
                acc1 = __builtin_amdgcn_mfma_f32_16x16x32_bf16(al1, bh, acc1, 0, 0, 0);
            }
            wait_bar();   // H0(t) now at the LLC
            #pragma unroll 2
            for (int kc = 0; kc < 16; ++kc) {
                const int kh = kc * 32 + kq;
                short8 bh = *(const short8*)&Wh[1][n][512 + kh];
                short8 bl = *(const short8*)&Wo[1][n][512 + kh];
                unsigned u0[8], u1[8];
                #pragma unroll
                for (int j = 0; j < 8; ++j) {
                    u0[j] = llc_ldu(&H0p[rA0 + kh + j]);
                    u1[j] = llc_ldu(&H0p[rA1 + kh + j]);
                }
                short8 ah0, al0, ah1, al1;
                #pragma unroll
                for (int j = 0; j < 8; ++j) {
                    ah0[j] = (short)(u0[j] & 0xFFFFu);
                    al0[j] = (short)(u0[j] >> 16);
                    ah1[j] = (short)(u1[j] & 0xFFFFu);
                    al1[j] = (short)(u1[j] >> 16);
                }
                acc0 = __builtin_amdgcn_mfma_f32_16x16x32_bf16(ah0, bh, acc0, 0, 0, 0);
                acc0 = __builtin_amdgcn_mfma_f32_16x16x32_bf16(ah0, bl, acc0, 0, 0, 0);
                acc0 = __builtin_amdgcn_mfma_f32_16x16x32_bf16(al0, bh, acc0, 0, 0, 0);
                acc1 = __builtin_amdgcn_mfma_f32_16x16x32_bf16(ah1, bh, acc1, 0, 0, 0);
                acc1 = __builtin_amdgcn_mfma_f32_16x16x32_bf16(ah1, bl, acc1, 0, 0, 0);
                acc1 = __builtin_amdgcn_mfma_f32_16x16x32_bf16(al1, bh, acc1, 0, 0, 0);
            }
            const float bs = bias_s[1][n];
            #pragma unroll
            for (int r = 0; r < 4; ++r) {
                gbuf[wm + rq + r][n]      = acc0[r] + bs;
                gbuf[wm + 16 + rq + r][n] = acc1[r] + bs;
            }
            __syncthreads();
            #pragma unroll
            for (int it = tid; it < 512; it += 256) {
                const int m = it >> 2, d = it & 3;
                const float gi = gbuf[m][d],     gf = gbuf[m][4 + d];
                const float gg = gbuf[m][8 + d], go = gbuf[m][12 + d];
                const float cn = sigm(gf) * carr[m][d] + sigm(gi) * tanhf(gg);
                carr[m][d] = cn;
                const float hv = sigm(go) * tanhf(cn);
                llc_stu(&H1f[m * 512 + d0 + d], __builtin_bit_cast(unsigned, hv));
            }
            arrive();   // barrier 2t+2: publish H1f(t)
        }
    }

    // epilogue: final FC row block = LN(h1(T-1)) -> slot L_-1
    wait_bar();
    ln_stats();
    if (w < 32) {
        const int rb = w * 4;
        for (int idx = tid; idx < 2048; idx += 256) {
            const int m = rb + (idx >> 9), k = idx & 511;
            const float v = llc_ldf(&H1f[m * 512 + k]);
            const float o = fmaf(fmaf(v, rs_s[m], -murs_s[m]), gam_s[k], bet_s[k]);
            Hnb[(((long)(L_ - 1)) * B_ + m) * D_ + k] = f2bf_rne(o);
        }
    }
}

// ---------------------------------------------------------------------------
// FC GEMM: C[m][n] = A[m][:].W[n][:] + bias[n]; m=(t-1)*128+b scatter.
// ---------------------------------------------------------------------------
__launch_bounds__(256)
__global__ void gemm_fc(const short* __restrict__ A,
                        const short* __restrict__ Wt,
                        const float* __restrict__ bias,
                        float* __restrict__ out) {
    __shared__ __align__(16) short As[128 * 40];
    __shared__ __align__(16) short Bs[128 * 40];
    const int tid = threadIdx.x;
    const int m0 = blockIdx.x * 128;
    const int n0 = blockIdx.y * 128;
    const int lrow = tid >> 1;
    const int lcol = (tid & 1) * 16;
    const int w = tid >> 6;
    const int lane = tid & 63;
    const int wm = (w >> 1) * 64;
    const int wn = (w & 1) * 64;

    f32x4 acc[4][4];
    #pragma unroll
    for (int i = 0; i < 4; ++i)
        #pragma unroll
        for (int j = 0; j < 4; ++j)
            acc[i][j] = (f32x4){0.f, 0.f, 0.f, 0.f};

    for (int kc = 0; kc < 16; ++kc) {
        const int kg = kc * 32;
        {
            const float4* src = reinterpret_cast<const float4*>(
                A + (long)(m0 + lrow) * D_ + kg + lcol);
            float4 v0 = src[0];
            float4 v1 = src[1];
            float4* dst = reinterpret_cast<float4*>(&As[lrow * 40 + lcol]);
            dst[0] = v0;
            dst[1] = v1;
        }
        {
            const int nn = n0 + lrow;
            float4 v0 = {0.f, 0.f, 0.f, 0.f}, v1 = {0.f, 0.f, 0.f, 0.f};
            if (nn < V_) {
                const float4* src = reinterpret_cast<const float4*>(
                    Wt + (long)nn * D_ + kg + lcol);
                v0 = src[0];
                v1 = src[1];
            }
            float4* dst = reinterpret_cast<float4*>(&Bs[lrow * 40 + lcol]);
            dst[0] = v0;
            dst[1] = v1;
        }
        __syncthreads();
        const int kcol = (lane >> 4) * 8;
        const int rsel = lane & 15;
        short8 a[4], bf[4];
        #pragma unroll
        for (int i = 0; i < 4; ++i)
            a[i] = *reinterpret_cast<const short8*>(&As[(wm + i * 16 + rsel) * 40 + kcol]);
        #pragma unroll
        for (int j = 0; j < 4; ++j)
            bf[j] = *reinterpret_cast<const short8*>(&Bs[(wn + j * 16 + rsel) * 40 + kcol]);
        #pragma unroll
        for (int i = 0; i < 4; ++i)
            #pragma unroll
            for (int j = 0; j < 4; ++j)
                acc[i][j] = __builtin_amdgcn_mfma_f32_16x16x32_bf16(a[i], bf[j], acc[i][j], 0, 0, 0);
        __syncthreads();
    }

    const int rquad = (lane >> 4) * 4;
    const int ncol = lane & 15;
    #pragma unroll
    for (int i = 0; i < 4; ++i) {
        #pragma unroll
        for (int j = 0; j < 4; ++j) {
            const int ngl = n0 + wn + j * 16 + ncol;
            if (ngl < V_) {
                const float bv = bias[ngl];
                #pragma unroll
                for (int r = 0; r < 4; ++r) {
                    const int mgl = m0 + wm + i * 16 + rquad + r;
                    const int tt = mgl >> 7;
                    const int bb = mgl & 127;
                    out[((long)bb * L_ + tt) * V_ + ngl] = acc[i][j][r] + bv;
                }
            }
        }
    }
}

// ---------------------------------------------------------------------------
// log-softmax, 2 passes (|logits| <= ~35 so exp-sum is fp32-safe w/o shift)
// ---------------------------------------------------------------------------
__global__ void logsoftmax_kernel(float* __restrict__ out) {
    __shared__ float red[256];
    const long row = blockIdx.x;
    float* p = out + row * V_;
    float4* p4 = reinterpret_cast<float4*>(p);
    const int tid = threadIdx.x;
    float s = 0.f;
    for (int i = tid; i < V_ / 4; i += 256) {
        float4 v = p4[i];
        s += __expf(v.x) + __expf(v.y) + __expf(v.z) + __expf(v.w);
    }
    red[tid] = s;
    __syncthreads();
    for (int st = 128; st > 0; st >>= 1) {
        if (tid < st) red[tid] += red[tid + st];
        __syncthreads();
    }
    const float ls = logf(red[0]);
    for (int i = tid; i < V_ / 4; i += 256) {
        float4 v = p4[i];
        v.x -= ls; v.y -= ls; v.z -= ls; v.w -= ls;
        p4[i] = v;
    }
}

// ---------------------------------------------------------------------------
extern "C" void kernel_launch(void* const* d_in, const int* in_sizes, int n_in,
                              void* d_out, int out_size, void* d_ws, size_t ws_size,
                              hipStream_t stream) {
    const float* features = (const float*)d_in[0];
    const int*   caption  = (const int*)d_in[1];
    const float* embW     = (const float*)d_in[2];
    const float* W_ih     = (const float*)d_in[3];
    const float* W_hh     = (const float*)d_in[4];
    const float* b_ih     = (const float*)d_in[5];
    const float* b_hh     = (const float*)d_in[6];
    const float* ln_g     = (const float*)d_in[7];
    const float* ln_b     = (const float*)d_in[8];
    const float* fc_W     = (const float*)d_in[9];
    const float* fc_b     = (const float*)d_in[10];
    float* out = (float*)d_out;

    char* ws = (char*)d_ws;
    int*      syncv = (int*)ws;      ws += 64;
    short*    Xhi   = (short*)ws;    ws += (size_t)T_ * B_ * D_ * 2;   // 4,325,376
    short*    Xlo   = (short*)ws;    ws += (size_t)T_ * B_ * D_ * 2;
    unsigned* H0p   = (unsigned*)ws; ws += (size_t)B_ * D_ * 4;        // 262,144
    float*    H1f   = (float*)ws;    ws += (size_t)B_ * D_ * 4;        // 262,144
    short*    Hnb   = (short*)ws;    ws += (size_t)L_ * B_ * D_ * 2;   // 4,194,304
    short*    fcWb  = (short*)ws;    ws += (size_t)V_ * D_ * 2;        // 10,240,000

    prep_kernel<<<2048, 256, 0, stream>>>(features, caption, embW, fc_W,
                                          Xhi, Xlo, fcWb, syncv);

    lstm_persist<<<NWG, 256, 0, stream>>>(Xhi, Xlo, W_ih, W_hh, b_ih, b_hh,
                                          ln_g, ln_b, H0p, H1f, Hnb,
                                          syncv);

    gemm_fc<<<dim3(32, 79), 256, 0, stream>>>(Hnb, fcWb, fc_b, out);
    logsoftmax_kernel<<<4096, 256, 0, stream>>>(out);
}

// Round 4
// 1773.199 us; speedup vs baseline: 2.3585x; 2.3585x over previous
//
#include <hip/hip_runtime.h>

#define B_ 128
#define D_ 512
#define T_ 33
#define L_ 32
#define V_ 10000
#define NWG 128

typedef short short8 __attribute__((ext_vector_type(8)));
typedef float f32x4 __attribute__((ext_vector_type(4)));

__device__ __forceinline__ short f2bf_rne(float f) {
    unsigned u = __builtin_bit_cast(unsigned, f);
    unsigned r = (u + 0x7FFFu + ((u >> 16) & 1u)) >> 16;
    return (short)r;
}
// truncation split: v ~= hi + lo with ~17 mantissa bits total
__device__ __forceinline__ void split2(float v, short& hi, short& lo) {
    unsigned u = __builtin_bit_cast(unsigned, v);
    hi = (short)(u >> 16);
    float hif = __builtin_bit_cast(float, u & 0xFFFF0000u);
    lo = (short)(__builtin_bit_cast(unsigned, v - hif) >> 16);
}
__device__ __forceinline__ float sigm(float x) {
    return 1.0f / (1.0f + __expf(-x));
}

// LLC-coherent store (sc0+sc1 write-through; no cache-maintenance needed on
// the writer side). Used ONLY for cross-WG data stores; reads stay cached+
// vectorized behind one acquire fence per barrier.
__device__ __forceinline__ void llc_stu(void* p, unsigned v) {
    __hip_atomic_store((unsigned*)p, v, __ATOMIC_RELAXED,
                       __HIP_MEMORY_SCOPE_SYSTEM);
}

// ---------------------------------------------------------------------------
// prep: split X (features|emb) into hi/lo bf16, fc_W -> bf16 (RNE), zero flags
// ---------------------------------------------------------------------------
__global__ void prep_kernel(const float* __restrict__ features,
                            const int* __restrict__ caption,
                            const float* __restrict__ embW,
                            const float* __restrict__ fcW,
                            short* __restrict__ Xhi,
                            short* __restrict__ Xlo,
                            short* __restrict__ fcWb,
                            int* __restrict__ syncv) {
    const long NX = (long)T_ * B_ * D_;          // 2,162,688
    const long NW = (long)V_ * D_;               // 5,120,000
    const long total = NX + NW;
    long gid = (long)blockIdx.x * blockDim.x + threadIdx.x;
    if (gid < NWG) syncv[gid] = 0;               // arrival flags
    for (long idx = gid; idx < total; idx += (long)gridDim.x * blockDim.x) {
        if (idx < NX) {
            int t = (int)(idx / (B_ * D_));
            int r = (int)(idx % (B_ * D_));
            int b = r >> 9;
            int d = r & 511;
            float v;
            if (t == 0) v = features[r];
            else        v = embW[(long)caption[b * L_ + (t - 1)] * D_ + d];
            short hi, lo;
            split2(v, hi, lo);
            Xhi[idx] = hi;
            Xlo[idx] = lo;
        } else {
            long j = idx - NX;
            fcWb[j] = f2bf_rne(fcW[j]);
        }
    }
}

// ---------------------------------------------------------------------------
// Persistent LSTM, split-bf16 MFMA (hi/lo x3 products => ~fp32 precision).
// 128 WGs; WG w owns d-cols [4w, 4w+4) across all 4 gates, both layers.
// LN of the h-carry folded into layer-0 W_hh (gamma pre-scaled, beta->bias).
//
// Sync design (round 4):
//   - flag-array barrier: NO atomic RMWs. arrive = syncthreads (vmcnt0
//     drains the LLC data stores) + one relaxed system store of the WG's
//     monotonic barrier count to flags[w]. wait = wave 0 gathers all 128
//     flags with two per-lane relaxed system loads + __all, then ONE
//     acquire fence (the only cache-maintenance op per barrier).
//   - cross-WG data WRITES are sc0+sc1 (write-through to LLC) -> no wbl2.
//   - cross-WG data READS are normal cached vectorized loads (float4/uint4)
//     behind the acquire fence.
//   - x-half MFMAs (X-only dependency) issued between arrive and wait.
// ---------------------------------------------------------------------------
__global__ __launch_bounds__(256)
void lstm_persist(const short* __restrict__ Xhi, const short* __restrict__ Xlo,
                  const float* __restrict__ Wih, const float* __restrict__ Whh,
                  const float* __restrict__ bih, const float* __restrict__ bhh,
                  const float* __restrict__ lng, const float* __restrict__ lnb,
                  unsigned* __restrict__ H0p, float* __restrict__ H1f,
                  short* __restrict__ Hnb, int* __restrict__ syncv) {
    __shared__ __align__(16) short Wh[2][16][1032];   // 66 KB (hi)
    __shared__ __align__(16) short Wo[2][16][1032];   // 66 KB (lo)
    __shared__ float gbuf[128][17];
    __shared__ float carr[128][4];
    __shared__ float rs_s[128], murs_s[128];
    __shared__ float gam_s[512], bet_s[512];
    __shared__ float bias_s[2][16];
    __shared__ float bconst_s[16];

    const int tid  = threadIdx.x;
    const int w    = blockIdx.x;
    const int d0   = w * 4;
    const int wave = tid >> 6;
    const int lane = tid & 63;
    const int wm   = wave * 32;
    const int n    = lane & 15;
    const int kq   = (lane >> 4) * 8;

    // ---------------- preload ----------------
    for (int idx = tid; idx < 512; idx += 256) {
        gam_s[idx] = lng[idx];
        bet_s[idx] = lnb[idx];
    }
    if (tid < 32) {
        int l = tid >> 4, nn = tid & 15;
        int row = (nn >> 2) * 512 + d0 + (nn & 3);
        bias_s[l][nn] = bih[l * 2048 + row] + bhh[l * 2048 + row];
    }
    for (int idx = tid; idx < 2 * 16 * 1024; idx += 256) {
        int l = idx >> 14;
        int nn = (idx >> 10) & 15;
        int k = idx & 1023;
        int row = (nn >> 2) * 512 + d0 + (nn & 3);
        float v = (k < 512) ? Wih[((long)(l * 2048 + row)) * 512 + k]
                            : Whh[((long)(l * 2048 + row)) * 512 + (k - 512)];
        if (l == 0 && k >= 512) v *= lng[k - 512];   // fold gamma into Whh0
        short hi, lo;
        split2(v, hi, lo);
        Wh[l][nn][k] = hi;
        Wo[l][nn][k] = lo;
    }
    // bconst[c] = sum_k beta[k] * Whh0[row(c)][k]  (unfolded weights)
    {
        const int c = tid >> 4, kc = tid & 15;
        const int row = (c >> 2) * 512 + d0 + (c & 3);
        float s = 0.f;
        for (int k = kc * 32; k < kc * 32 + 32; ++k)
            s += lnb[k] * Whh[(long)row * 512 + k];
        gbuf[c][kc] = s;
    }
    for (int idx = tid; idx < 512; idx += 256) carr[idx >> 2][idx & 3] = 0.f;
    __syncthreads();
    if (tid < 16) {
        float s2 = 0.f;
        for (int i = 0; i < 16; ++i) s2 += gbuf[tid][i];
        bconst_s[tid] = s2;
    }
    __syncthreads();

    int* flags = syncv;          // NWG dwords, one per WG
    int nb = 0;                  // this WG's barrier arrival count

    // arrive: syncthreads drains every wave's LLC stores (vmcnt0 before
    // s_barrier), then ONE relaxed system store to this WG's own flag.
    // No RMW, no fence, no cache walk.
    auto arrive = [&]() {
        __syncthreads();
        ++nb;
        if (tid == 0)
            __hip_atomic_store(&flags[w], nb, __ATOMIC_RELAXED,
                               __HIP_MEMORY_SCOPE_SYSTEM);
    };
    // wait: wave 0 gathers all 128 flags (2 per-lane LLC loads, parallel
    // across channels), exits when min >= nb. One acquire fence per WG.
    auto wait_bar = [&]() {
        if (wave == 0) {
            const int tgt = nb;
            for (;;) {
                int f0 = __hip_atomic_load(&flags[lane], __ATOMIC_RELAXED,
                                           __HIP_MEMORY_SCOPE_SYSTEM);
                int f1 = __hip_atomic_load(&flags[64 + lane], __ATOMIC_RELAXED,
                                           __HIP_MEMORY_SCOPE_SYSTEM);
                if (__all(f0 >= tgt && f1 >= tgt)) break;
                __builtin_amdgcn_s_sleep(1);
            }
        }
        __syncthreads();
        __builtin_amdgcn_fence(__ATOMIC_ACQUIRE, "agent");
    };

    // LN row stats of H1f, 2 threads per row (cached float4 reads).
    auto ln_stats = [&]() {
        const int row = tid & 127, half = tid >> 7;
        const float4* hp = (const float4*)&H1f[row * 512 + half * 256];
        float s = 0.f, s2 = 0.f;
        #pragma unroll 16
        for (int i = 0; i < 64; ++i) {
            float4 v = hp[i];
            s  += v.x + v.y + v.z + v.w;
            s2 += v.x * v.x + v.y * v.y + v.z * v.z + v.w * v.w;
        }
        gbuf[row][half * 2]     = s;
        gbuf[row][half * 2 + 1] = s2;
        __syncthreads();
        if (tid < 128) {
            const float ss  = gbuf[tid][0] + gbuf[tid][2];
            const float ss2 = gbuf[tid][1] + gbuf[tid][3];
            const float mu  = ss * (1.0f / 512.0f);
            const float var = ss2 * (1.0f / 512.0f) - mu * mu;
            const float rs  = rsqrtf(var + 1e-5f);
            rs_s[tid]   = rs;
            murs_s[tid] = mu * rs;
        }
        __syncthreads();
    };

    const int rA0 = (wm + n) * 512;
    const int rA1 = (wm + 16 + n) * 512;
    const int rq  = (lane >> 4) * 4;

    for (int t = 0; t < T_; ++t) {
        const short* xh = Xhi + (long)t * B_ * D_;
        const short* xl = Xlo + (long)t * B_ * D_;

        // ================= phase 0 (layer 0) =================
        {
            f32x4 acc0 = {0.f, 0.f, 0.f, 0.f};
            f32x4 acc1 = {0.f, 0.f, 0.f, 0.f};
            // x-half: depends only on X — runs while the H1 barrier propagates
            #pragma unroll 4
            for (int kc = 0; kc < 16; ++kc) {
                const int kg = kc * 32 + kq;
                short8 bh = *(const short8*)&Wh[0][n][kg];
                short8 bl = *(const short8*)&Wo[0][n][kg];
                short8 ah0 = *(const short8*)&xh[rA0 + kg];
                short8 al0 = *(const short8*)&xl[rA0 + kg];
                short8 ah1 = *(const short8*)&xh[rA1 + kg];
                short8 al1 = *(const short8*)&xl[rA1 + kg];
                acc0 = __builtin_amdgcn_mfma_f32_16x16x32_bf16(ah0, bh, acc0, 0, 0, 0);
                acc0 = __builtin_amdgcn_mfma_f32_16x16x32_bf16(ah0, bl, acc0, 0, 0, 0);
                acc0 = __builtin_amdgcn_mfma_f32_16x16x32_bf16(al0, bh, acc0, 0, 0, 0);
                acc1 = __builtin_amdgcn_mfma_f32_16x16x32_bf16(ah1, bh, acc1, 0, 0, 0);
                acc1 = __builtin_amdgcn_mfma_f32_16x16x32_bf16(ah1, bl, acc1, 0, 0, 0);
                acc1 = __builtin_amdgcn_mfma_f32_16x16x32_bf16(al1, bh, acc1, 0, 0, 0);
            }
            if (t > 0) {
                wait_bar();          // H1f(t-1) visible (LLC) + L1/L2 inv'd
                ln_stats();          // rs_s/murs_s of h1(t-1)
                // h-half: H1 fp32 cached float4 reads, LN applied inline
                const float r0 = rs_s[wm + n],      m0 = murs_s[wm + n];
                const float r1 = rs_s[wm + 16 + n], m1 = murs_s[wm + 16 + n];
                #pragma unroll 2
                for (int kc = 0; kc < 16; ++kc) {
                    const int kh = kc * 32 + kq;
                    short8 bh = *(const short8*)&Wh[0][n][512 + kh];
                    short8 bl = *(const short8*)&Wo[0][n][512 + kh];
                    float va[8], vb[8];
                    *(float4*)&va[0] = *(const float4*)&H1f[rA0 + kh];
                    *(float4*)&va[4] = *(const float4*)&H1f[rA0 + kh + 4];
                    *(float4*)&vb[0] = *(const float4*)&H1f[rA1 + kh];
                    *(float4*)&vb[4] = *(const float4*)&H1f[rA1 + kh + 4];
                    short8 ah0, al0, ah1, al1;
                    #pragma unroll
                    for (int j = 0; j < 8; ++j) {
                        float f0 = fmaf(va[j], r0, -m0);
                        float f1 = fmaf(vb[j], r1, -m1);
                        short h_, l_;
                        split2(f0, h_, l_); ah0[j] = h_; al0[j] = l_;
                        split2(f1, h_, l_); ah1[j] = h_; al1[j] = l_;
                    }
                    acc0 = __builtin_amdgcn_mfma_f32_16x16x32_bf16(ah0, bh, acc0, 0, 0, 0);
                    acc0 = __builtin_amdgcn_mfma_f32_16x16x32_bf16(ah0, bl, acc0, 0, 0, 0);
                    acc0 = __builtin_amdgcn_mfma_f32_16x16x32_bf16(al0, bh, acc0, 0, 0, 0);
                    acc1 = __builtin_amdgcn_mfma_f32_16x16x32_bf16(ah1, bh, acc1, 0, 0, 0);
                    acc1 = __builtin_amdgcn_mfma_f32_16x16x32_bf16(ah1, bl, acc1, 0, 0, 0);
                    acc1 = __builtin_amdgcn_mfma_f32_16x16x32_bf16(al1, bh, acc1, 0, 0, 0);
                }
                // materialize LN'd bf16 rows of h1(t-1) for the FC GEMM
                // (safe: H1f rewritten only after ALL WGs pass barrier 2t+1,
                //  which we arrive at below, after these reads)
                if (w < 32 && t >= 2) {
                    const int rb = w * 4;
                    for (int idx = tid; idx < 2048; idx += 256) {
                        const int m = rb + (idx >> 9), k = idx & 511;
                        const float v = H1f[m * 512 + k];
                        const float o = fmaf(fmaf(v, rs_s[m], -murs_s[m]), gam_s[k], bet_s[k]);
                        Hnb[(((long)(t - 2)) * B_ + m) * D_ + k] = f2bf_rne(o);
                    }
                }
            }
            const float bs = bias_s[0][n] + (t > 0 ? bconst_s[n] : 0.f);
            #pragma unroll
            for (int r = 0; r < 4; ++r) {
                gbuf[wm + rq + r][n]      = acc0[r] + bs;
                gbuf[wm + 16 + rq + r][n] = acc1[r] + bs;
            }
            __syncthreads();
            #pragma unroll
            for (int it = tid; it < 512; it += 256) {
                const int m = it >> 2, d = it & 3;
                const float gi = gbuf[m][d],     gf = gbuf[m][4 + d];
                const float gg = gbuf[m][8 + d], go = gbuf[m][12 + d];
                const float cn = sigm(gf) * carr[m][d] + sigm(gi) * tanhf(gg);
                carr[m][d] = cn;
                const float hv = sigm(go) * tanhf(cn);
                short hi_, lo_;
                split2(hv, hi_, lo_);
                const unsigned pk = (unsigned)(unsigned short)hi_
                                  | ((unsigned)(unsigned short)lo_ << 16);
                llc_stu(&H0p[m * 512 + d0 + d], pk);   // write-through to LLC
            }
            arrive();   // barrier 2t+1: publish H0(t)
        }

        // ================= phase 1 (layer 1) =================
        {
            f32x4 acc0 = {0.f, 0.f, 0.f, 0.f};
            f32x4 acc1 = {0.f, 0.f, 0.f, 0.f};
            // x-half first: hides the H0 barrier propagation
            #pragma unroll 4
            for (int kc = 0; kc < 16; ++kc) {
                const int kg = kc * 32 + kq;
                short8 bh = *(const short8*)&Wh[1][n][kg];
                short8 bl = *(const short8*)&Wo[1][n][kg];
                short8 ah0 = *(const short8*)&xh[rA0 + kg];
                short8 al0 = *(const short8*)&xl[rA0 + kg];
                short8 ah1 = *(const short8*)&xh[rA1 + kg];
                short8 al1 = *(const short8*)&xl[rA1 + kg];
                acc0 = __builtin_amdgcn_mfma_f32_16x16x32_bf16(ah0, bh, acc0, 0, 0, 0);
                acc0 = __builtin_amdgcn_mfma_f32_16x16x32_bf16(ah0, bl, acc0, 0, 0, 0);
                acc0 = __builtin_amdgcn_mfma_f32_16x16x32_bf16(al0, bh, acc0, 0, 0, 0);
                acc1 = __builtin_amdgcn_mfma_f32_16x16x32_bf16(ah1, bh, acc1, 0, 0, 0);
                acc1 = __builtin_amdgcn_mfma_f32_16x16x32_bf16(ah1, bl, acc1, 0, 0, 0);
                acc1 = __builtin_amdgcn_mfma_f32_16x16x32_bf16(al1, bh, acc1, 0, 0, 0);
            }
            wait_bar();   // H0(t) visible (LLC) + L1/L2 inv'd
            #pragma unroll 2
            for (int kc = 0; kc < 16; ++kc) {
                const int kh = kc * 32 + kq;
                short8 bh = *(const short8*)&Wh[1][n][512 + kh];
                short8 bl = *(const short8*)&Wo[1][n][512 + kh];
                unsigned u0[8], u1[8];
                *(uint4*)&u0[0] = *(const uint4*)&H0p[rA0 + kh];
                *(uint4*)&u0[4] = *(const uint4*)&H0p[rA0 + kh + 4];
                *(uint4*)&u1[0] = *(const uint4*)&H0p[rA1 + kh];
                *(uint4*)&u1[4] = *(const uint4*)&H0p[rA1 + kh + 4];
                short8 ah0, al0, ah1, al1;
                #pragma unroll
                for (int j = 0; j < 8; ++j) {
                    ah0[j] = (short)(u0[j] & 0xFFFFu);
                    al0[j] = (short)(u0[j] >> 16);
                    ah1[j] = (short)(u1[j] & 0xFFFFu);
                    al1[j] = (short)(u1[j] >> 16);
                }
                acc0 = __builtin_amdgcn_mfma_f32_16x16x32_bf16(ah0, bh, acc0, 0, 0, 0);
                acc0 = __builtin_amdgcn_mfma_f32_16x16x32_bf16(ah0, bl, acc0, 0, 0, 0);
                acc0 = __builtin_amdgcn_mfma_f32_16x16x32_bf16(al0, bh, acc0, 0, 0, 0);
                acc1 = __builtin_amdgcn_mfma_f32_16x16x32_bf16(ah1, bh, acc1, 0, 0, 0);
                acc1 = __builtin_amdgcn_mfma_f32_16x16x32_bf16(ah1, bl, acc1, 0, 0, 0);
                acc1 = __builtin_amdgcn_mfma_f32_16x16x32_bf16(al1, bh, acc1, 0, 0, 0);
            }
            const float bs = bias_s[1][n];
            #pragma unroll
            for (int r = 0; r < 4; ++r) {
                gbuf[wm + rq + r][n]      = acc0[r] + bs;
                gbuf[wm + 16 + rq + r][n] = acc1[r] + bs;
            }
            __syncthreads();
            #pragma unroll
            for (int it = tid; it < 512; it += 256) {
                const int m = it >> 2, d = it & 3;
                const float gi = gbuf[m][d],     gf = gbuf[m][4 + d];
                const float gg = gbuf[m][8 + d], go = gbuf[m][12 + d];
                const float cn = sigm(gf) * carr[m][d] + sigm(gi) * tanhf(gg);
                carr[m][d] = cn;
                const float hv = sigm(go) * tanhf(cn);
                llc_stu(&H1f[m * 512 + d0 + d],
                        __builtin_bit_cast(unsigned, hv));   // write-through
            }
            arrive();   // barrier 2t+2: publish H1f(t)
        }
    }

    // epilogue: final FC row block = LN(h1(T-1)) -> slot L_-1
    wait_bar();
    ln_stats();
    if (w < 32) {
        const int rb = w * 4;
        for (int idx = tid; idx < 2048; idx += 256) {
            const int m = rb + (idx >> 9), k = idx & 511;
            const float v = H1f[m * 512 + k];
            const float o = fmaf(fmaf(v, rs_s[m], -murs_s[m]), gam_s[k], bet_s[k]);
            Hnb[(((long)(L_ - 1)) * B_ + m) * D_ + k] = f2bf_rne(o);
        }
    }
}

// ---------------------------------------------------------------------------
// FC GEMM: C[m][n] = A[m][:].W[n][:] + bias[n]; m=(t-1)*128+b scatter.
// ---------------------------------------------------------------------------
__launch_bounds__(256)
__global__ void gemm_fc(const short* __restrict__ A,
                        const short* __restrict__ Wt,
                        const float* __restrict__ bias,
                        float* __restrict__ out) {
    __shared__ __align__(16) short As[128 * 40];
    __shared__ __align__(16) short Bs[128 * 40];
    const int tid = threadIdx.x;
    const int m0 = blockIdx.x * 128;
    const int n0 = blockIdx.y * 128;
    const int lrow = tid >> 1;
    const int lcol = (tid & 1) * 16;
    const int w = tid >> 6;
    const int lane = tid & 63;
    const int wm = (w >> 1) * 64;
    const int wn = (w & 1) * 64;

    f32x4 acc[4][4];
    #pragma unroll
    for (int i = 0; i < 4; ++i)
        #pragma unroll
        for (int j = 0; j < 4; ++j)
            acc[i][j] = (f32x4){0.f, 0.f, 0.f, 0.f};

    for (int kc = 0; kc < 16; ++kc) {
        const int kg = kc * 32;
        {
            const float4* src = reinterpret_cast<const float4*>(
                A + (long)(m0 + lrow) * D_ + kg + lcol);
            float4 v0 = src[0];
            float4 v1 = src[1];
            float4* dst = reinterpret_cast<float4*>(&As[lrow * 40 + lcol]);
            dst[0] = v0;
            dst[1] = v1;
        }
        {
            const int nn = n0 + lrow;
            float4 v0 = {0.f, 0.f, 0.f, 0.f}, v1 = {0.f, 0.f, 0.f, 0.f};
            if (nn < V_) {
                const float4* src = reinterpret_cast<const float4*>(
                    Wt + (long)nn * D_ + kg + lcol);
                v0 = src[0];
                v1 = src[1];
            }
            float4* dst = reinterpret_cast<float4*>(&Bs[lrow * 40 + lcol]);
            dst[0] = v0;
            dst[1] = v1;
        }
        __syncthreads();
        const int kcol = (lane >> 4) * 8;
        const int rsel = lane & 15;
        short8 a[4], bf[4];
        #pragma unroll
        for (int i = 0; i < 4; ++i)
            a[i] = *reinterpret_cast<const short8*>(&As[(wm + i * 16 + rsel) * 40 + kcol]);
        #pragma unroll
        for (int j = 0; j < 4; ++j)
            bf[j] = *reinterpret_cast<const short8*>(&Bs[(wn + j * 16 + rsel) * 40 + kcol]);
        #pragma unroll
        for (int i = 0; i < 4; ++i)
            #pragma unroll
            for (int j = 0; j < 4; ++j)
                acc[i][j] = __builtin_amdgcn_mfma_f32_16x16x32_bf16(a[i], bf[j], acc[i][j], 0, 0, 0);
        __syncthreads();
    }

    const int rquad = (lane >> 4) * 4;
    const int ncol = lane & 15;
    #pragma unroll
    for (int i = 0; i < 4; ++i) {
        #pragma unroll
        for (int j = 0; j < 4; ++j) {
            const int ngl = n0 + wn + j * 16 + ncol;
            if (ngl < V_) {
                const float bv = bias[ngl];
                #pragma unroll
                for (int r = 0; r < 4; ++r) {
                    const int mgl = m0 + wm + i * 16 + rquad + r;
                    const int tt = mgl >> 7;
                    const int bb = mgl & 127;
                    out[((long)bb * L_ + tt) * V_ + ngl] = acc[i][j][r] + bv;
                }
            }
        }
    }
}

// ---------------------------------------------------------------------------
// log-softmax, 2 passes (|logits| <= ~35 so exp-sum is fp32-safe w/o shift)
// ---------------------------------------------------------------------------
__global__ void logsoftmax_kernel(float* __restrict__ out) {
    __shared__ float red[256];
    const long row = blockIdx.x;
    float* p = out + row * V_;
    float4* p4 = reinterpret_cast<float4*>(p);
    const int tid = threadIdx.x;
    float s = 0.f;
    for (int i = tid; i < V_ / 4; i += 256) {
        float4 v = p4[i];
        s += __expf(v.x) + __expf(v.y) + __expf(v.z) + __expf(v.w);
    }
    red[tid] = s;
    __syncthreads();
    for (int st = 128; st > 0; st >>= 1) {
        if (tid < st) red[tid] += red[tid + st];
        __syncthreads();
    }
    const float ls = logf(red[0]);
    for (int i = tid; i < V_ / 4; i += 256) {
        float4 v = p4[i];
        v.x -= ls; v.y -= ls; v.z -= ls; v.w -= ls;
        p4[i] = v;
    }
}

// ---------------------------------------------------------------------------
extern "C" void kernel_launch(void* const* d_in, const int* in_sizes, int n_in,
                              void* d_out, int out_size, void* d_ws, size_t ws_size,
                              hipStream_t stream) {
    const float* features = (const float*)d_in[0];
    const int*   caption  = (const int*)d_in[1];
    const float* embW     = (const float*)d_in[2];
    const float* W_ih     = (const float*)d_in[3];
    const float* W_hh     = (const float*)d_in[4];
    const float* b_ih     = (const float*)d_in[5];
    const float* b_hh     = (const float*)d_in[6];
    const float* ln_g     = (const float*)d_in[7];
    const float* ln_b     = (const float*)d_in[8];
    const float* fc_W     = (const float*)d_in[9];
    const float* fc_b     = (const float*)d_in[10];
    float* out = (float*)d_out;

    char* ws = (char*)d_ws;
    int*      syncv = (int*)ws;      ws += 512;                        // 128 flags
    short*    Xhi   = (short*)ws;    ws += (size_t)T_ * B_ * D_ * 2;   // 4,325,376
    short*    Xlo   = (short*)ws;    ws += (size_t)T_ * B_ * D_ * 2;
    unsigned* H0p   = (unsigned*)ws; ws += (size_t)B_ * D_ * 4;        // 262,144
    float*    H1f   = (float*)ws;    ws += (size_t)B_ * D_ * 4;        // 262,144
    short*    Hnb   = (short*)ws;    ws += (size_t)L_ * B_ * D_ * 2;   // 4,194,304
    short*    fcWb  = (short*)ws;    ws += (size_t)V_ * D_ * 2;        // 10,240,000

    prep_kernel<<<2048, 256, 0, stream>>>(features, caption, embW, fc_W,
                                          Xhi, Xlo, fcWb, syncv);

    lstm_persist<<<NWG, 256, 0, stream>>>(Xhi, Xlo, W_ih, W_hh, b_ih, b_hh,
                                          ln_g, ln_b, H0p, H1f, Hnb,
                                          syncv);

    gemm_fc<<<dim3(32, 79), 256, 0, stream>>>(Hnb, fcWb, fc_b, out);
    logsoftmax_kernel<<<4096, 256, 0, stream>>>(out);
}

// Round 6
// 1673.731 us; speedup vs baseline: 2.4987x; 1.0594x over previous
//
#include <hip/hip_runtime.h>

#define B_ 128
#define D_ 512
#define T_ 33
#define L_ 32
#define V_ 10000
#define NWG 128
#define THREADS 512

typedef short short8 __attribute__((ext_vector_type(8)));
typedef float f32x4 __attribute__((ext_vector_type(4)));

__device__ __forceinline__ short f2bf_rne(float f) {
    unsigned u = __builtin_bit_cast(unsigned, f);
    unsigned r = (u + 0x7FFFu + ((u >> 16) & 1u)) >> 16;
    return (short)r;
}
// truncation split: v ~= hi + lo with ~17 mantissa bits total
__device__ __forceinline__ void split2(float v, short& hi, short& lo) {
    unsigned u = __builtin_bit_cast(unsigned, v);
    hi = (short)(u >> 16);
    float hif = __builtin_bit_cast(float, u & 0xFFFF0000u);
    lo = (short)(__builtin_bit_cast(unsigned, v - hif) >> 16);
}
__device__ __forceinline__ float sigm(float x) {
    return 1.0f / (1.0f + __expf(-x));
}
// reconstruct hi+lo from packed word (== what the MFMA consumes)
__device__ __forceinline__ float unpack2f(unsigned u) {
    return __builtin_bit_cast(float, u << 16)
         + __builtin_bit_cast(float, u & 0xFFFF0000u);
}

// LLC-coherent store (sc0+sc1 write-through; no cache-maintenance needed on
// the writer side). Used ONLY for cross-WG data stores; reads stay cached+
// vectorized behind one acquire fence per barrier.
__device__ __forceinline__ void llc_stu(void* p, unsigned v) {
    __hip_atomic_store((unsigned*)p, v, __ATOMIC_RELAXED,
                       __HIP_MEMORY_SCOPE_SYSTEM);
}

// ---------------------------------------------------------------------------
// prep: split X (features|emb) into hi/lo bf16, fc_W -> bf16 (RNE), zero flags
// ---------------------------------------------------------------------------
__global__ void prep_kernel(const float* __restrict__ features,
                            const int* __restrict__ caption,
                            const float* __restrict__ embW,
                            const float* __restrict__ fcW,
                            short* __restrict__ Xhi,
                            short* __restrict__ Xlo,
                            short* __restrict__ fcWb,
                            int* __restrict__ syncv) {
    const long NX = (long)T_ * B_ * D_;          // 2,162,688
    const long NW = (long)V_ * D_;               // 5,120,000
    const long total = NX + NW;
    long gid = (long)blockIdx.x * blockDim.x + threadIdx.x;
    if (gid < NWG) syncv[gid] = 0;               // arrival flags
    for (long idx = gid; idx < total; idx += (long)gridDim.x * blockDim.x) {
        if (idx < NX) {
            int t = (int)(idx / (B_ * D_));
            int r = (int)(idx % (B_ * D_));
            int b = r >> 9;
            int d = r & 511;
            float v;
            if (t == 0) v = features[r];
            else        v = embW[(long)caption[b * L_ + (t - 1)] * D_ + d];
            short hi, lo;
            split2(v, hi, lo);
            Xhi[idx] = hi;
            Xlo[idx] = lo;
        } else {
            long j = idx - NX;
            fcWb[j] = f2bf_rne(fcW[j]);
        }
    }
}

// ---------------------------------------------------------------------------
// Persistent LSTM, split-bf16 MFMA (hi/lo x3 products => ~fp32 precision).
// 128 WGs x 512 threads (8 waves, 16 batch-rows each -> 2 waves/SIMD TLP).
// WG w owns d-cols [4w, 4w+4) across all 4 gates, both layers.
//
// Deferred LayerNorm: h1 is stored as packed RAW hi|lo bf16 (H1p). Phase-0
// h-half MFMAs run on raw h1; LN enters afterwards on the accumulator:
//   gate_h[r,c] = rs_r * (Wg.h)[r,c] - (mu_r*rs_r) * Sg[c] + bconst[c]
// with Wg = gamma-folded Whh0, Sg[c] = sum_k Wg[c,k], bconst[c] = sum_k
// beta_k*Whh0[c,k] (both precomputed).
//
// Sync: flag-array barrier (no RMW): arrive = syncthreads + relaxed system
// store of the WG's monotonic count; wait = wave 0 gathers 128 flags with two
// per-lane relaxed system loads + __all, then ONE wave-0 acquire fence
// (cache-wide inv) before the closing syncthreads orders all waves' reads.
// Bounded poll (~20ms) turns a would-be deadlock into a wrong-answer report
// instead of a container kill (diagnostic safety net; 200x normal-wait margin).
// ---------------------------------------------------------------------------
__global__ __launch_bounds__(THREADS)
void lstm_persist(const short* __restrict__ Xhi, const short* __restrict__ Xlo,
                  const float* __restrict__ Wih, const float* __restrict__ Whh,
                  const float* __restrict__ bih, const float* __restrict__ bhh,
                  const float* __restrict__ lng, const float* __restrict__ lnb,
                  unsigned* __restrict__ H0p, unsigned* __restrict__ H1p,
                  short* __restrict__ Hnb, int* __restrict__ syncv) {
    __shared__ __align__(16) short Wh[2][16][1032];   // 66 KB (hi)
    __shared__ __align__(16) short Wo[2][16][1032];   // 66 KB (lo)
    __shared__ float gbuf[128][17];
    __shared__ float carr[128][4];
    __shared__ float rs_s[128], murs_s[128];
    __shared__ float gam_s[512], bet_s[512];
    __shared__ float bias_s[2][16];
    __shared__ float bconst_s[16];
    __shared__ float sgam_s[16];

    const int tid  = threadIdx.x;
    const int w    = blockIdx.x;
    const int d0   = w * 4;
    const int wave = tid >> 6;
    const int lane = tid & 63;
    const int wm   = wave * 16;            // 8 waves x 16 rows
    const int n    = lane & 15;
    const int kq   = (lane >> 4) * 8;

    // ---------------- preload ----------------
    gam_s[tid & 511] = lng[tid & 511];     // 512 threads, one elem each
    bet_s[tid & 511] = lnb[tid & 511];
    if (tid < 32) {
        int l = tid >> 4, nn = tid & 15;
        int row = (nn >> 2) * 512 + d0 + (nn & 3);
        bias_s[l][nn] = bih[l * 2048 + row] + bhh[l * 2048 + row];
    }
    for (int idx = tid; idx < 2 * 16 * 1024; idx += THREADS) {
        int l = idx >> 14;
        int nn = (idx >> 10) & 15;
        int k = idx & 1023;
        int row = (nn >> 2) * 512 + d0 + (nn & 3);
        float v = (k < 512) ? Wih[((long)(l * 2048 + row)) * 512 + k]
                            : Whh[((long)(l * 2048 + row)) * 512 + (k - 512)];
        if (l == 0 && k >= 512) v *= lng[k - 512];   // fold gamma into Whh0
        short hi, lo;
        split2(v, hi, lo);
        Wh[l][nn][k] = hi;
        Wo[l][nn][k] = lo;
    }
    // bconst[c] = sum_k beta[k]*Whh0[row(c)][k];  sgam[c] = sum_k gam[k]*Whh0
    if (tid < 256) {
        const int c = tid >> 4, kc = tid & 15;
        const int row = (c >> 2) * 512 + d0 + (c & 3);
        float sb = 0.f, sg = 0.f;
        for (int k = kc * 32; k < kc * 32 + 32; ++k) {
            const float wv = Whh[(long)row * 512 + k];
            sb += lnb[k] * wv;
            sg += lng[k] * wv;
        }
        gbuf[c][kc]      = sb;
        gbuf[64 + c][kc] = sg;
    }
    carr[tid >> 2][tid & 3] = 0.f;
    __syncthreads();
    if (tid < 32) {
        const int c = tid & 15;
        const int base = (tid >= 16) ? 64 + c : c;
        float s = 0.f;
        for (int i = 0; i < 16; ++i) s += gbuf[base][i];
        if (tid < 16) bconst_s[c] = s;
        else          sgam_s[c]   = s;
    }
    __syncthreads();

    int* flags = syncv;          // NWG dwords, one per WG
    int nb = 0;                  // this WG's barrier arrival count

    auto arrive = [&]() {
        __syncthreads();         // drains all waves' LLC stores (vmcnt0)
        ++nb;
        if (tid == 0)
            __hip_atomic_store(&flags[w], nb, __ATOMIC_RELAXED,
                               __HIP_MEMORY_SCOPE_SYSTEM);
    };
    auto wait_bar = [&]() {
        if (wave == 0) {
            const int tgt = nb;
            int iter = 0;
            for (;;) {
                int f0 = __hip_atomic_load(&flags[lane], __ATOMIC_RELAXED,
                                           __HIP_MEMORY_SCOPE_SYSTEM);
                int f1 = __hip_atomic_load(&flags[64 + lane], __ATOMIC_RELAXED,
                                           __HIP_MEMORY_SCOPE_SYSTEM);
                if (__all(f0 >= tgt && f1 >= tgt)) break;
                if (++iter > 65536) break;   // safety net: report, don't hang
                __builtin_amdgcn_s_sleep(1);
            }
            // one cache-wide inv per WG; closing syncthreads orders all
            // waves' subsequent loads behind it
            __builtin_amdgcn_fence(__ATOMIC_ACQUIRE, "agent");
        }
        __syncthreads();
    };

    // LN row stats from packed H1p (4 threads/row; L2-hot after h-half MFMA)
    auto ln_stats = [&]() {
        const int row = tid & 127, q = tid >> 7;
        const uint4* hp = (const uint4*)&H1p[row * 512 + q * 128];
        float s = 0.f, s2 = 0.f;
        #pragma unroll 8
        for (int i = 0; i < 32; ++i) {
            uint4 u = hp[i];
            #pragma unroll
            for (int e = 0; e < 4; ++e) {
                const float v = unpack2f((&u.x)[e]);
                s  += v;
                s2 += v * v;
            }
        }
        gbuf[row][q * 2]     = s;
        gbuf[row][q * 2 + 1] = s2;
        __syncthreads();
        if (tid < 128) {
            const float ss  = gbuf[tid][0] + gbuf[tid][2] + gbuf[tid][4] + gbuf[tid][6];
            const float ss2 = gbuf[tid][1] + gbuf[tid][3] + gbuf[tid][5] + gbuf[tid][7];
            const float mu  = ss * (1.0f / 512.0f);
            const float var = ss2 * (1.0f / 512.0f) - mu * mu;
            const float rs  = rsqrtf(var + 1e-5f);
            rs_s[tid]   = rs;
            murs_s[tid] = mu * rs;
        }
        __syncthreads();
    };

    const int rA0 = (wm + n) * 512;
    const int rq  = (lane >> 4) * 4;

    for (int t = 0; t < T_; ++t) {
        const short* xh = Xhi + (long)t * B_ * D_;
        const short* xl = Xlo + (long)t * B_ * D_;

        // ================= phase 0 (layer 0) =================
        {
            f32x4 accx = {0.f, 0.f, 0.f, 0.f};
            f32x4 acch = {0.f, 0.f, 0.f, 0.f};
            // x-half: depends only on X — runs while the barrier propagates
            #pragma unroll 4
            for (int kc = 0; kc < 16; ++kc) {
                const int kg = kc * 32 + kq;
                short8 bh = *(const short8*)&Wh[0][n][kg];
                short8 bl = *(const short8*)&Wo[0][n][kg];
                short8 ah = *(const short8*)&xh[rA0 + kg];
                short8 al = *(const short8*)&xl[rA0 + kg];
                accx = __builtin_amdgcn_mfma_f32_16x16x32_bf16(ah, bh, accx, 0, 0, 0);
                accx = __builtin_amdgcn_mfma_f32_16x16x32_bf16(ah, bl, accx, 0, 0, 0);
                accx = __builtin_amdgcn_mfma_f32_16x16x32_bf16(al, bh, accx, 0, 0, 0);
            }
            if (t > 0) {
                wait_bar();          // H1p(t-1) visible + caches inv'd
                // h-half on RAW packed h1 (LN deferred to accumulator)
                #pragma unroll 4
                for (int kc = 0; kc < 16; ++kc) {
                    const int kh = kc * 32 + kq;
                    short8 bh = *(const short8*)&Wh[0][n][512 + kh];
                    short8 bl = *(const short8*)&Wo[0][n][512 + kh];
                    unsigned u[8];
                    *(uint4*)&u[0] = *(const uint4*)&H1p[rA0 + kh];
                    *(uint4*)&u[4] = *(const uint4*)&H1p[rA0 + kh + 4];
                    short8 ah, al;
                    #pragma unroll
                    for (int j = 0; j < 8; ++j) {
                        ah[j] = (short)(u[j] & 0xFFFFu);
                        al[j] = (short)(u[j] >> 16);
                    }
                    acch = __builtin_amdgcn_mfma_f32_16x16x32_bf16(ah, bh, acch, 0, 0, 0);
                    acch = __builtin_amdgcn_mfma_f32_16x16x32_bf16(ah, bl, acch, 0, 0, 0);
                    acch = __builtin_amdgcn_mfma_f32_16x16x32_bf16(al, bh, acch, 0, 0, 0);
                }
                ln_stats();          // rs_s/murs_s of h1(t-1)
                // materialize LN'd bf16 rows of h1(t-1) for the FC GEMM
                if (w < 32 && t >= 2) {
                    const int rb = w * 4;
                    for (int idx = tid; idx < 2048; idx += THREADS) {
                        const int m = rb + (idx >> 9), k = idx & 511;
                        const float v = unpack2f(H1p[m * 512 + k]);
                        const float o = fmaf(fmaf(v, rs_s[m], -murs_s[m]), gam_s[k], bet_s[k]);
                        Hnb[(((long)(t - 2)) * B_ + m) * D_ + k] = f2bf_rne(o);
                    }
                }
            }
            const float bs = bias_s[0][n] + (t > 0 ? bconst_s[n] : 0.f);
            const float sg = sgam_s[n];
            #pragma unroll
            for (int r = 0; r < 4; ++r) {
                const int row = wm + rq + r;
                float g = accx[r] + bs;
                if (t > 0) g += acch[r] * rs_s[row] - murs_s[row] * sg;
                gbuf[row][n] = g;
            }
            __syncthreads();
            {
                const int m = tid >> 2, d = tid & 3;
                const float gi = gbuf[m][d],     gf = gbuf[m][4 + d];
                const float gg = gbuf[m][8 + d], go = gbuf[m][12 + d];
                const float cn = sigm(gf) * carr[m][d] + sigm(gi) * tanhf(gg);
                carr[m][d] = cn;
                const float hv = sigm(go) * tanhf(cn);
                short hi_, lo_;
                split2(hv, hi_, lo_);
                const unsigned pk = (unsigned)(unsigned short)hi_
                                  | ((unsigned)(unsigned short)lo_ << 16);
                llc_stu(&H0p[m * 512 + d0 + d], pk);
            }
            arrive();   // barrier 2t+1: publish H0(t)
        }

        // ================= phase 1 (layer 1) =================
        {
            f32x4 acc = {0.f, 0.f, 0.f, 0.f};
            // x-half first: hides the H0 barrier propagation
            #pragma unroll 4
            for (int kc = 0; kc < 16; ++kc) {
                const int kg = kc * 32 + kq;
                short8 bh = *(const short8*)&Wh[1][n][kg];
                short8 bl = *(const short8*)&Wo[1][n][kg];
                short8 ah = *(const short8*)&xh[rA0 + kg];
                short8 al = *(const short8*)&xl[rA0 + kg];
                acc = __builtin_amdgcn_mfma_f32_16x16x32_bf16(ah, bh, acc, 0, 0, 0);
                acc = __builtin_amdgcn_mfma_f32_16x16x32_bf16(ah, bl, acc, 0, 0, 0);
                acc = __builtin_amdgcn_mfma_f32_16x16x32_bf16(al, bh, acc, 0, 0, 0);
            }
            wait_bar();   // H0p(t) visible + caches inv'd
            #pragma unroll 4
            for (int kc = 0; kc < 16; ++kc) {
                const int kh = kc * 32 + kq;
                short8 bh = *(const short8*)&Wh[1][n][512 + kh];
                short8 bl = *(const short8*)&Wo[1][n][512 + kh];
                unsigned u[8];
                *(uint4*)&u[0] = *(const uint4*)&H0p[rA0 + kh];
                *(uint4*)&u[4] = *(const uint4*)&H0p[rA0 + kh + 4];
                short8 ah, al;
                #pragma unroll
                for (int j = 0; j < 8; ++j) {
                    ah[j] = (short)(u[j] & 0xFFFFu);
                    al[j] = (short)(u[j] >> 16);
                }
                acc = __builtin_amdgcn_mfma_f32_16x16x32_bf16(ah, bh, acc, 0, 0, 0);
                acc = __builtin_amdgcn_mfma_f32_16x16x32_bf16(ah, bl, acc, 0, 0, 0);
                acc = __builtin_amdgcn_mfma_f32_16x16x32_bf16(al, bh, acc, 0, 0, 0);
            }
            const float bs = bias_s[1][n];
            #pragma unroll
            for (int r = 0; r < 4; ++r)
                gbuf[wm + rq + r][n] = acc[r] + bs;
            __syncthreads();
            {
                const int m = tid >> 2, d = tid & 3;
                const float gi = gbuf[m][d],     gf = gbuf[m][4 + d];
                const float gg = gbuf[m][8 + d], go = gbuf[m][12 + d];
                const float cn = sigm(gf) * carr[m][d] + sigm(gi) * tanhf(gg);
                carr[m][d] = cn;
                const float hv = sigm(go) * tanhf(cn);
                short hi_, lo_;
                split2(hv, hi_, lo_);
                const unsigned pk = (unsigned)(unsigned short)hi_
                                  | ((unsigned)(unsigned short)lo_ << 16);
                llc_stu(&H1p[m * 512 + d0 + d], pk);   // RAW h1, packed
            }
            arrive();   // barrier 2t+2: publish H1p(t)
        }
    }

    // epilogue: final FC row block = LN(h1(T-1)) -> slot L_-1
    wait_bar();
    ln_stats();
    if (w < 32) {
        const int rb = w * 4;
        for (int idx = tid; idx < 2048; idx += THREADS) {
            const int m = rb + (idx >> 9), k = idx & 511;
            const float v = unpack2f(H1p[m * 512 + k]);
            const float o = fmaf(fmaf(v, rs_s[m], -murs_s[m]), gam_s[k], bet_s[k]);
            Hnb[(((long)(L_ - 1)) * B_ + m) * D_ + k] = f2bf_rne(o);
        }
    }
}

// ---------------------------------------------------------------------------
// FC GEMM: C[m][n] = A[m][:].W[n][:] + bias[n]; m=(t-1)*128+b scatter.
// ---------------------------------------------------------------------------
__launch_bounds__(256)
__global__ void gemm_fc(const short* __restrict__ A,
                        const short* __restrict__ Wt,
                        const float* __restrict__ bias,
                        float* __restrict__ out) {
    __shared__ __align__(16) short As[128 * 40];
    __shared__ __align__(16) short Bs[128 * 40];
    const int tid = threadIdx.x;
    const int m0 = blockIdx.x * 128;
    const int n0 = blockIdx.y * 128;
    const int lrow = tid >> 1;
    const int lcol = (tid & 1) * 16;
    const int w = tid >> 6;
    const int lane = tid & 63;
    const int wm = (w >> 1) * 64;
    const int wn = (w & 1) * 64;

    f32x4 acc[4][4];
    #pragma unroll
    for (int i = 0; i < 4; ++i)
        #pragma unroll
        for (int j = 0; j < 4; ++j)
            acc[i][j] = (f32x4){0.f, 0.f, 0.f, 0.f};

    for (int kc = 0; kc < 16; ++kc) {
        const int kg = kc * 32;
        {
            const float4* src = reinterpret_cast<const float4*>(
                A + (long)(m0 + lrow) * D_ + kg + lcol);
            float4 v0 = src[0];
            float4 v1 = src[1];
            float4* dst = reinterpret_cast<float4*>(&As[lrow * 40 + lcol]);
            dst[0] = v0;
            dst[1] = v1;
        }
        {
            const int nn = n0 + lrow;
            float4 v0 = {0.f, 0.f, 0.f, 0.f}, v1 = {0.f, 0.f, 0.f, 0.f};
            if (nn < V_) {
                const float4* src = reinterpret_cast<const float4*>(
                    Wt + (long)nn * D_ + kg + lcol);
                v0 = src[0];
                v1 = src[1];
            }
            float4* dst = reinterpret_cast<float4*>(&Bs[lrow * 40 + lcol]);
            dst[0] = v0;
            dst[1] = v1;
        }
        __syncthreads();
        const int kcol = (lane >> 4) * 8;
        const int rsel = lane & 15;
        short8 a[4], bf[4];
        #pragma unroll
        for (int i = 0; i < 4; ++i)
            a[i] = *reinterpret_cast<const short8*>(&As[(wm + i * 16 + rsel) * 40 + kcol]);
        #pragma unroll
        for (int j = 0; j < 4; ++j)
            bf[j] = *reinterpret_cast<const short8*>(&Bs[(wn + j * 16 + rsel) * 40 + kcol]);
        #pragma unroll
        for (int i = 0; i < 4; ++i)
            #pragma unroll
            for (int j = 0; j < 4; ++j)
                acc[i][j] = __builtin_amdgcn_mfma_f32_16x16x32_bf16(a[i], bf[j], acc[i][j], 0, 0, 0);
        __syncthreads();
    }

    const int rquad = (lane >> 4) * 4;
    const int ncol = lane & 15;
    #pragma unroll
    for (int i = 0; i < 4; ++i) {
        #pragma unroll
        for (int j = 0; j < 4; ++j) {
            const int ngl = n0 + wn + j * 16 + ncol;
            if (ngl < V_) {
                const float bv = bias[ngl];
                #pragma unroll
                for (int r = 0; r < 4; ++r) {
                    const int mgl = m0 + wm + i * 16 + rquad + r;
                    const int tt = mgl >> 7;
                    const int bb = mgl & 127;
                    out[((long)bb * L_ + tt) * V_ + ngl] = acc[i][j][r] + bv;
                }
            }
        }
    }
}

// ---------------------------------------------------------------------------
// log-softmax, 2 passes (|logits| <= ~35 so exp-sum is fp32-safe w/o shift)
// ---------------------------------------------------------------------------
__global__ void logsoftmax_kernel(float* __restrict__ out) {
    __shared__ float red[256];
    const long row = blockIdx.x;
    float* p = out + row * V_;
    float4* p4 = reinterpret_cast<float4*>(p);
    const int tid = threadIdx.x;
    float s = 0.f;
    for (int i = tid; i < V_ / 4; i += 256) {
        float4 v = p4[i];
        s += __expf(v.x) + __expf(v.y) + __expf(v.z) + __expf(v.w);
    }
    red[tid] = s;
    __syncthreads();
    for (int st = 128; st > 0; st >>= 1) {
        if (tid < st) red[tid] += red[tid + st];
        __syncthreads();
    }
    const float ls = logf(red[0]);
    for (int i = tid; i < V_ / 4; i += 256) {
        float4 v = p4[i];
        v.x -= ls; v.y -= ls; v.z -= ls; v.w -= ls;
        p4[i] = v;
    }
}

// ---------------------------------------------------------------------------
extern "C" void kernel_launch(void* const* d_in, const int* in_sizes, int n_in,
                              void* d_out, int out_size, void* d_ws, size_t ws_size,
                              hipStream_t stream) {
    const float* features = (const float*)d_in[0];
    const int*   caption  = (const int*)d_in[1];
    const float* embW     = (const float*)d_in[2];
    const float* W_ih     = (const float*)d_in[3];
    const float* W_hh     = (const float*)d_in[4];
    const float* b_ih     = (const float*)d_in[5];
    const float* b_hh     = (const float*)d_in[6];
    const float* ln_g     = (const float*)d_in[7];
    const float* ln_b     = (const float*)d_in[8];
    const float* fc_W     = (const float*)d_in[9];
    const float* fc_b     = (const float*)d_in[10];
    float* out = (float*)d_out;

    char* ws = (char*)d_ws;
    int*      syncv = (int*)ws;      ws += 512;                        // 128 flags
    short*    Xhi   = (short*)ws;    ws += (size_t)T_ * B_ * D_ * 2;   // 4,325,376
    short*    Xlo   = (short*)ws;    ws += (size_t)T_ * B_ * D_ * 2;
    unsigned* H0p   = (unsigned*)ws; ws += (size_t)B_ * D_ * 4;        // 262,144
    unsigned* H1p   = (unsigned*)ws; ws += (size_t)B_ * D_ * 4;        // 262,144
    short*    Hnb   = (short*)ws;    ws += (size_t)L_ * B_ * D_ * 2;   // 4,194,304
    short*    fcWb  = (short*)ws;    ws += (size_t)V_ * D_ * 2;        // 10,240,000

    prep_kernel<<<2048, 256, 0, stream>>>(features, caption, embW, fc_W,
                                          Xhi, Xlo, fcWb, syncv);

    lstm_persist<<<NWG, THREADS, 0, stream>>>(Xhi, Xlo, W_ih, W_hh, b_ih, b_hh,
                                              ln_g, ln_b, H0p, H1p, Hnb,
                                              syncv);

    gemm_fc<<<dim3(32, 79), 256, 0, stream>>>(Hnb, fcWb, fc_b, out);
    logsoftmax_kernel<<<4096, 256, 0, stream>>>(out);
}